// Round 1
// baseline (736.408 us; speedup 1.0000x reference)
//
#include <hip/hip_runtime.h>

// GNN encoder layer: LN -> mean-aggregate over edges -> SAGEConv -> relu -> +residual
// Pipeline (all on `stream`, no sync ops, graph-capture safe):
//  1. ln_kernel      : h = LN(x)*gamma+beta, stored bf16 into A_cat[:,512:1024]
//  2. wconv_kernel   : W_cat[j, 0:512]=bf16(W_l[j,:]), W_cat[j,512:1024]=bf16(W_r[j,:])
//  3. zero + hist    : cnt[d] = in-degree
//  4. scan1/2/3      : row_start = exclusive_scan(cnt); cur = row_start
//  5. scatter_kernel : sorted_src = src indices grouped by dst (CSR)
//  6. agg_kernel     : mean rows (bf16) into A_cat[:,0:512]  (wave/node, L3-resident gather)
//  7. gemm_kernel    : out = relu(A_cat @ W_cat^T + b_l) + residual  (m97-style MFMA bf16)

#define D_DIM 512

typedef __bf16 bf16x8 __attribute__((ext_vector_type(8)));
typedef float f32x4 __attribute__((ext_vector_type(4)));

__device__ __forceinline__ unsigned short f2bf(float f) {
  unsigned u = __float_as_uint(f);
  u += 0x7fffu + ((u >> 16) & 1u);   // RNE
  return (unsigned short)(u >> 16);
}
__device__ __forceinline__ float bflo(unsigned u) { return __uint_as_float(u << 16); }
__device__ __forceinline__ float bfhi(unsigned u) { return __uint_as_float(u & 0xffff0000u); }
__device__ __forceinline__ unsigned packbf2(float lo, float hi) {
  return (unsigned)f2bf(lo) | ((unsigned)f2bf(hi) << 16);
}

// ---------------- LayerNorm: one wave per row, 8 floats/lane ----------------
__global__ void ln_kernel(const float* __restrict__ x, const float* __restrict__ gamma,
                          const float* __restrict__ beta, unsigned short* __restrict__ Acat,
                          int n) {
  int lane = threadIdx.x & 63;
  int row = blockIdx.x * 4 + (threadIdx.x >> 6);
  if (row >= n) return;
  const float* xr = x + (size_t)row * D_DIM + lane * 8;
  float4 a = *(const float4*)xr;
  float4 b = *(const float4*)(xr + 4);
  float sum = a.x + a.y + a.z + a.w + b.x + b.y + b.z + b.w;
  float sq = a.x * a.x + a.y * a.y + a.z * a.z + a.w * a.w +
             b.x * b.x + b.y * b.y + b.z * b.z + b.w * b.w;
#pragma unroll
  for (int m = 1; m < 64; m <<= 1) {
    sum += __shfl_xor(sum, m, 64);
    sq  += __shfl_xor(sq, m, 64);
  }
  float mu = sum * (1.0f / D_DIM);
  float var = sq * (1.0f / D_DIM) - mu * mu;
  float rs = rsqrtf(var + 1e-5f);
  const float* gp = gamma + lane * 8;
  const float* bp = beta + lane * 8;
  float4 g0 = *(const float4*)gp, g1 = *(const float4*)(gp + 4);
  float4 e0 = *(const float4*)bp, e1 = *(const float4*)(bp + 4);
  float h0 = (a.x - mu) * rs * g0.x + e0.x;
  float h1 = (a.y - mu) * rs * g0.y + e0.y;
  float h2 = (a.z - mu) * rs * g0.z + e0.z;
  float h3 = (a.w - mu) * rs * g0.w + e0.w;
  float h4 = (b.x - mu) * rs * g1.x + e1.x;
  float h5 = (b.y - mu) * rs * g1.y + e1.y;
  float h6 = (b.z - mu) * rs * g1.z + e1.z;
  float h7 = (b.w - mu) * rs * g1.w + e1.w;
  uint4 st = { packbf2(h0, h1), packbf2(h2, h3), packbf2(h4, h5), packbf2(h6, h7) };
  *(uint4*)(Acat + (size_t)row * 1024 + 512 + lane * 8) = st;
}

// ---------------- W concat + bf16 convert ----------------
__global__ void wconv_kernel(const float* __restrict__ Wl, const float* __restrict__ Wr,
                             unsigned short* __restrict__ Wcat) {
  int id = blockIdx.x * 256 + threadIdx.x;  // 0 .. 512*512-1
  int j = id >> 9, k = id & 511;
  Wcat[(size_t)j * 1024 + k] = f2bf(Wl[id]);
  Wcat[(size_t)j * 1024 + 512 + k] = f2bf(Wr[id]);
}

// ---------------- CSR build ----------------
__global__ void zero_kernel(int* __restrict__ p, int n) {
  int i = blockIdx.x * 256 + threadIdx.x;
  if (i < n) p[i] = 0;
}

__global__ void hist_kernel(const int* __restrict__ dst, int nE, int* __restrict__ cnt) {
  int e = blockIdx.x * 256 + threadIdx.x;
  if (e < nE) atomicAdd(&cnt[dst[e]], 1);
}

__global__ void scan1_kernel(const int* __restrict__ cnt, int n,
                             int* __restrict__ excl, int* __restrict__ bsums) {
  __shared__ int wsum[16];
  int gid = blockIdx.x * 1024 + threadIdx.x;
  int lane = threadIdx.x & 63, wave = threadIdx.x >> 6;
  int v = (gid < n) ? cnt[gid] : 0;
  int s = v;
#pragma unroll
  for (int d = 1; d < 64; d <<= 1) {
    int t = __shfl_up(s, d, 64);
    if (lane >= d) s += t;
  }
  if (lane == 63) wsum[wave] = s;
  __syncthreads();
  if (wave == 0) {
    int ws = (lane < 16) ? wsum[lane] : 0;
#pragma unroll
    for (int d = 1; d < 16; d <<= 1) {
      int t = __shfl_up(ws, d, 64);
      if (lane >= d) ws += t;
    }
    if (lane < 16) wsum[lane] = ws;
  }
  __syncthreads();
  int incl = s + ((wave > 0) ? wsum[wave - 1] : 0);
  if (gid < n) excl[gid] = incl - v;
  if (threadIdx.x == 1023) bsums[blockIdx.x] = incl;
}

__global__ void scan2_kernel(int* __restrict__ bsums, int nb) {
  int lane = threadIdx.x;  // 64 threads, nb <= 64
  int v = (lane < nb) ? bsums[lane] : 0;
  int s = v;
#pragma unroll
  for (int d = 1; d < 64; d <<= 1) {
    int t = __shfl_up(s, d, 64);
    if (lane >= d) s += t;
  }
  if (lane < nb) bsums[lane] = s - v;  // exclusive
}

__global__ void scan3_kernel(int* __restrict__ rowst, int* __restrict__ cur,
                             const int* __restrict__ bsums, int n, int nE) {
  int gid = blockIdx.x * 1024 + threadIdx.x;
  if (gid < n) {
    int r = rowst[gid] + bsums[blockIdx.x];
    rowst[gid] = r;
    cur[gid] = r;
  }
  if (gid == 0) rowst[n] = nE;
}

__global__ void scatter_kernel(const int* __restrict__ src, const int* __restrict__ dst,
                               int nE, int* __restrict__ cur, int* __restrict__ sorted_src) {
  int e = blockIdx.x * 256 + threadIdx.x;
  if (e < nE) {
    int p = atomicAdd(&cur[dst[e]], 1);
    sorted_src[p] = src[e];
  }
}

// ---------------- aggregation: one wave per dst node ----------------
__device__ __forceinline__ void acc_row(float* acc, uint4 r) {
  acc[0] += bflo(r.x); acc[1] += bfhi(r.x);
  acc[2] += bflo(r.y); acc[3] += bfhi(r.y);
  acc[4] += bflo(r.z); acc[5] += bfhi(r.z);
  acc[6] += bflo(r.w); acc[7] += bfhi(r.w);
}

__global__ void agg_kernel(unsigned short* __restrict__ Acat,
                           const int* __restrict__ rowst,
                           const int* __restrict__ sorted_src, int n) {
  int lane = threadIdx.x & 63;
  int node = blockIdx.x * 4 + (threadIdx.x >> 6);
  if (node >= n) return;
  int s0 = rowst[node], s1 = rowst[node + 1];
  float acc[8] = {0.f, 0.f, 0.f, 0.f, 0.f, 0.f, 0.f, 0.f};
  const unsigned short* hbase = Acat + 512 + lane * 8;
  int e = s0;
  for (; e + 3 < s1; e += 4) {  // unroll 4 for MLP
    int i0 = sorted_src[e], i1 = sorted_src[e + 1];
    int i2 = sorted_src[e + 2], i3 = sorted_src[e + 3];
    uint4 r0 = *(const uint4*)(hbase + (size_t)i0 * 1024);
    uint4 r1 = *(const uint4*)(hbase + (size_t)i1 * 1024);
    uint4 r2 = *(const uint4*)(hbase + (size_t)i2 * 1024);
    uint4 r3 = *(const uint4*)(hbase + (size_t)i3 * 1024);
    acc_row(acc, r0); acc_row(acc, r1); acc_row(acc, r2); acc_row(acc, r3);
  }
  for (; e < s1; ++e) {
    int i0 = sorted_src[e];
    uint4 r0 = *(const uint4*)(hbase + (size_t)i0 * 1024);
    acc_row(acc, r0);
  }
  int deg = s1 - s0;
  float sc = (deg > 0) ? (1.0f / (float)deg) : 0.0f;
  uint4 st = { packbf2(acc[0] * sc, acc[1] * sc), packbf2(acc[2] * sc, acc[3] * sc),
               packbf2(acc[4] * sc, acc[5] * sc), packbf2(acc[6] * sc, acc[7] * sc) };
  *(uint4*)(Acat + (size_t)node * 1024 + lane * 8) = st;
}

// ---------------- GEMM: [Mpad x 1024] @ [512 x 1024]^T, m97 structure ----------------
__device__ __forceinline__ void async16(const unsigned short* g, char* lds) {
  __builtin_amdgcn_global_load_lds((const __attribute__((address_space(1))) void*)g,
                                   (__attribute__((address_space(3))) void*)lds, 16, 0, 0);
}

__global__ __launch_bounds__(256) void gemm_kernel(
    const unsigned short* __restrict__ A,  // [Mpad][1024] bf16 (mean | h)
    const unsigned short* __restrict__ B,  // [512][1024]  bf16 (W_l | W_r), row = out col
    const float* __restrict__ bias,        // b_l [512]
    const float* __restrict__ residual,    // x [M][512]
    float* __restrict__ out, int M) {
  __shared__ unsigned short sA[128 * 32];  // 8 KB
  __shared__ unsigned short sB[128 * 32];  // 8 KB
  const int K = 1024;
  int t = threadIdx.x;
  int lane = t & 63, wave = t >> 6;
  int quad = lane >> 4, l16 = lane & 15;
  int mb = blockIdx.x >> 2, nb = blockIdx.x & 3;  // 4 col-blocks adjacent -> A-tile L2 reuse
  int mBase = mb * 128, nBase = nb * 128;
  int wm = (wave & 1) * 64, wn = (wave >> 1) * 64;

  // staging: thread t loads 16B: row = t>>2 (+64 on issue 1), k-chunk = t&3
  const unsigned short* gA = A + (size_t)(mBase + (t >> 2)) * K + (t & 3) * 8;
  const unsigned short* gB = B + (size_t)(nBase + (t >> 2)) * K + (t & 3) * 8;
  char* lA0 = (char*)sA + wave * 1024;
  char* lA1 = (char*)sA + 4096 + wave * 1024;
  char* lB0 = (char*)sB + wave * 1024;
  char* lB1 = (char*)sB + 4096 + wave * 1024;

  f32x4 acc[4][4] = {};

  for (int ks = 0; ks < K; ks += 32) {
    __syncthreads();
    async16(gA + ks, lA0);
    async16(gA + (size_t)64 * K + ks, lA1);
    async16(gB + ks, lB0);
    async16(gB + (size_t)64 * K + ks, lB1);
    __syncthreads();  // compiler emits vmcnt(0) drain here
    bf16x8 af[4], bf[4];
#pragma unroll
    for (int i = 0; i < 4; ++i)
      af[i] = *(const bf16x8*)(sA + (wm + i * 16 + l16) * 32 + quad * 8);
#pragma unroll
    for (int j = 0; j < 4; ++j)
      bf[j] = *(const bf16x8*)(sB + (wn + j * 16 + l16) * 32 + quad * 8);
#pragma unroll
    for (int i = 0; i < 4; ++i)
#pragma unroll
      for (int j = 0; j < 4; ++j)
        acc[i][j] = __builtin_amdgcn_mfma_f32_16x16x32_bf16(af[i], bf[j], acc[i][j], 0, 0, 0);
  }

  float biasv[4];
#pragma unroll
  for (int j = 0; j < 4; ++j) biasv[j] = bias[nBase + wn + j * 16 + l16];
#pragma unroll
  for (int i = 0; i < 4; ++i) {
    int gr0 = mBase + wm + i * 16 + quad * 4;  // C/D: row = quad*4+reg, col = lane&15
#pragma unroll
    for (int j = 0; j < 4; ++j) {
      int col = nBase + wn + j * 16 + l16;
#pragma unroll
      for (int r = 0; r < 4; ++r) {
        int gr = gr0 + r;
        if (gr < M) {
          size_t idx = (size_t)gr * D_DIM + col;
          float v = acc[i][j][r] + biasv[j];
          out[idx] = fmaxf(v, 0.0f) + residual[idx];
        }
      }
    }
  }
}

// ---------------- launch ----------------
extern "C" void kernel_launch(void* const* d_in, const int* in_sizes, int n_in,
                              void* d_out, int out_size, void* d_ws, size_t ws_size,
                              hipStream_t stream) {
  const float* x = (const float*)d_in[0];
  const int* ei = (const int*)d_in[1];
  const float* Wl = (const float*)d_in[2];
  const float* bl = (const float*)d_in[3];
  const float* Wr = (const float*)d_in[4];
  const float* gamma = (const float*)d_in[5];
  const float* beta = (const float*)d_in[6];
  float* out = (float*)d_out;

  int n = in_sizes[0] / D_DIM;       // 50000
  int nE = in_sizes[1] / 2;          // 1500000
  const int* src = ei;
  const int* dstv = ei + nE;
  int Mpad = (n + 127) & ~127;       // 50048

  // ws layout (256B aligned chunks); total ~110 MB
  char* w = (char*)d_ws;
  size_t off = 0;
  auto carve = [&](size_t bytes) {
    char* p = w + off;
    off += (bytes + 255) & ~(size_t)255;
    return p;
  };
  unsigned short* Acat = (unsigned short*)carve((size_t)Mpad * 1024 * 2);
  unsigned short* Wcat = (unsigned short*)carve((size_t)512 * 1024 * 2);
  int* sorted = (int*)carve((size_t)nE * 4);
  int* cnt = (int*)carve((size_t)n * 4);
  int* rowst = (int*)carve((size_t)(n + 1) * 4);
  int* cur = (int*)carve((size_t)n * 4);
  int* bsums = (int*)carve(1024);
  if (off > ws_size) return;  // ws too small -> fail loudly via wrong output

  int nbScan = (n + 1023) / 1024;  // 49 (<=64 required by scan2)

  ln_kernel<<<(n + 3) / 4, 256, 0, stream>>>(x, gamma, beta, Acat, n);
  wconv_kernel<<<(512 * 512) / 256, 256, 0, stream>>>(Wl, Wr, Wcat);
  zero_kernel<<<(n + 255) / 256, 256, 0, stream>>>(cnt, n);
  hist_kernel<<<(nE + 255) / 256, 256, 0, stream>>>(dstv, nE, cnt);
  scan1_kernel<<<nbScan, 1024, 0, stream>>>(cnt, n, rowst, bsums);
  scan2_kernel<<<1, 64, 0, stream>>>(bsums, nbScan);
  scan3_kernel<<<nbScan, 1024, 0, stream>>>(rowst, cur, bsums, n, nE);
  scatter_kernel<<<(nE + 255) / 256, 256, 0, stream>>>(src, dstv, nE, cur, sorted);
  agg_kernel<<<(n + 3) / 4, 256, 0, stream>>>(Acat, rowst, sorted, n);
  gemm_kernel<<<(Mpad / 128) * 4, 256, 0, stream>>>(Acat, Wcat, bl, x, out, n);
}

// Round 2
// 652.263 us; speedup vs baseline: 1.1290x; 1.1290x over previous
//
#include <hip/hip_runtime.h>

// GNN encoder layer: LN -> mean-aggregate over edges -> SAGEConv -> relu -> +residual
// Pipeline (all on `stream`, graph-capture safe):
//  1. ln_kernel      : h = LN(x)*gamma+beta -> bf16 into A_cat[:,512:1024], fp8 copy into h8
//  2. wconv_kernel   : W_cat[j,0:512]=bf16(W_l[j,:]), W_cat[j,512:1024]=bf16(W_r[j,:])
//  3. zero + hist    : cnt[d] = in-degree
//  4. scan1/2/3      : row_start = exclusive_scan(cnt); cur(=cnt) = row_start
//  5. scatter_kernel : sorted_src = src indices grouped by dst (CSR)
//  6. agg_kernel     : mean of fp8 h rows (fp32 accum) -> bf16 into A_cat[:,0:512]
//  7. gemm_kernel    : out = relu(A_cat @ W_cat^T + b_l) + residual  (m97-style MFMA bf16)

#define D_DIM 512

typedef __bf16 bf16x8 __attribute__((ext_vector_type(8)));
typedef float f32x4 __attribute__((ext_vector_type(4)));
typedef float f32x2 __attribute__((ext_vector_type(2)));

__device__ __forceinline__ unsigned short f2bf(float f) {
  unsigned u = __float_as_uint(f);
  u += 0x7fffu + ((u >> 16) & 1u);   // RNE
  return (unsigned short)(u >> 16);
}
__device__ __forceinline__ float bflo(unsigned u) { return __uint_as_float(u << 16); }
__device__ __forceinline__ float bfhi(unsigned u) { return __uint_as_float(u & 0xffff0000u); }
__device__ __forceinline__ unsigned packbf2(float lo, float hi) {
  return (unsigned)f2bf(lo) | ((unsigned)f2bf(hi) << 16);
}

// ---------------- LayerNorm: one wave per row, 8 floats/lane ----------------
__global__ void ln_kernel(const float* __restrict__ x, const float* __restrict__ gamma,
                          const float* __restrict__ beta, unsigned short* __restrict__ Acat,
                          unsigned char* __restrict__ h8, int n, int use_fp8) {
  int lane = threadIdx.x & 63;
  int row = blockIdx.x * 4 + (threadIdx.x >> 6);
  if (row >= n) return;
  const float* xr = x + (size_t)row * D_DIM + lane * 8;
  float4 a = *(const float4*)xr;
  float4 b = *(const float4*)(xr + 4);
  float sum = a.x + a.y + a.z + a.w + b.x + b.y + b.z + b.w;
  float sq = a.x * a.x + a.y * a.y + a.z * a.z + a.w * a.w +
             b.x * b.x + b.y * b.y + b.z * b.z + b.w * b.w;
#pragma unroll
  for (int m = 1; m < 64; m <<= 1) {
    sum += __shfl_xor(sum, m, 64);
    sq  += __shfl_xor(sq, m, 64);
  }
  float mu = sum * (1.0f / D_DIM);
  float var = sq * (1.0f / D_DIM) - mu * mu;
  float rs = rsqrtf(var + 1e-5f);
  const float* gp = gamma + lane * 8;
  const float* bp = beta + lane * 8;
  float4 g0 = *(const float4*)gp, g1 = *(const float4*)(gp + 4);
  float4 e0 = *(const float4*)bp, e1 = *(const float4*)(bp + 4);
  float h0 = (a.x - mu) * rs * g0.x + e0.x;
  float h1 = (a.y - mu) * rs * g0.y + e0.y;
  float h2 = (a.z - mu) * rs * g0.z + e0.z;
  float h3 = (a.w - mu) * rs * g0.w + e0.w;
  float h4 = (b.x - mu) * rs * g1.x + e1.x;
  float h5 = (b.y - mu) * rs * g1.y + e1.y;
  float h6 = (b.z - mu) * rs * g1.z + e1.z;
  float h7 = (b.w - mu) * rs * g1.w + e1.w;
  uint4 st = { packbf2(h0, h1), packbf2(h2, h3), packbf2(h4, h5), packbf2(h6, h7) };
  *(uint4*)(Acat + (size_t)row * 1024 + 512 + lane * 8) = st;
  if (use_fp8) {
    int p0 = __builtin_amdgcn_cvt_pk_fp8_f32(h0, h1, 0, false);
    p0 = __builtin_amdgcn_cvt_pk_fp8_f32(h2, h3, p0, true);
    int p1 = __builtin_amdgcn_cvt_pk_fp8_f32(h4, h5, 0, false);
    p1 = __builtin_amdgcn_cvt_pk_fp8_f32(h6, h7, p1, true);
    uint2 st2 = { (unsigned)p0, (unsigned)p1 };
    *(uint2*)(h8 + (size_t)row * 512 + lane * 8) = st2;
  }
}

// ---------------- W concat + bf16 convert ----------------
__global__ void wconv_kernel(const float* __restrict__ Wl, const float* __restrict__ Wr,
                             unsigned short* __restrict__ Wcat) {
  int id = blockIdx.x * 256 + threadIdx.x;  // 0 .. 512*512-1
  int j = id >> 9, k = id & 511;
  Wcat[(size_t)j * 1024 + k] = f2bf(Wl[id]);
  Wcat[(size_t)j * 1024 + 512 + k] = f2bf(Wr[id]);
}

// ---------------- CSR build ----------------
__global__ void zero_kernel(int* __restrict__ p, int n) {
  int i = blockIdx.x * 256 + threadIdx.x;
  if (i < n) p[i] = 0;
}

__global__ void hist_kernel(const int* __restrict__ dst, int nE, int* __restrict__ cnt) {
  int e = blockIdx.x * 256 + threadIdx.x;
  if (e < nE) atomicAdd(&cnt[dst[e]], 1);
}

__global__ void scan1_kernel(const int* __restrict__ cnt, int n,
                             int* __restrict__ excl, int* __restrict__ bsums) {
  __shared__ int wsum[16];
  int gid = blockIdx.x * 1024 + threadIdx.x;
  int lane = threadIdx.x & 63, wave = threadIdx.x >> 6;
  int v = (gid < n) ? cnt[gid] : 0;
  int s = v;
#pragma unroll
  for (int d = 1; d < 64; d <<= 1) {
    int t = __shfl_up(s, d, 64);
    if (lane >= d) s += t;
  }
  if (lane == 63) wsum[wave] = s;
  __syncthreads();
  if (wave == 0) {
    int ws = (lane < 16) ? wsum[lane] : 0;
#pragma unroll
    for (int d = 1; d < 16; d <<= 1) {
      int t = __shfl_up(ws, d, 64);
      if (lane >= d) ws += t;
    }
    if (lane < 16) wsum[lane] = ws;
  }
  __syncthreads();
  int incl = s + ((wave > 0) ? wsum[wave - 1] : 0);
  if (gid < n) excl[gid] = incl - v;
  if (threadIdx.x == 1023) bsums[blockIdx.x] = incl;
}

__global__ void scan2_kernel(int* __restrict__ bsums, int nb) {
  int lane = threadIdx.x;  // 64 threads, nb <= 64
  int v = (lane < nb) ? bsums[lane] : 0;
  int s = v;
#pragma unroll
  for (int d = 1; d < 64; d <<= 1) {
    int t = __shfl_up(s, d, 64);
    if (lane >= d) s += t;
  }
  if (lane < nb) bsums[lane] = s - v;  // exclusive
}

__global__ void scan3_kernel(int* __restrict__ rowst, int* __restrict__ cur,
                             const int* __restrict__ bsums, int n, int nE) {
  int gid = blockIdx.x * 1024 + threadIdx.x;
  if (gid < n) {
    int r = rowst[gid] + bsums[blockIdx.x];
    rowst[gid] = r;
    cur[gid] = r;
  }
  if (gid == 0) rowst[n] = nE;
}

__global__ void scatter_kernel(const int* __restrict__ src, const int* __restrict__ dst,
                               int nE, int* __restrict__ cur, int* __restrict__ sorted_src) {
  int e = blockIdx.x * 256 + threadIdx.x;
  if (e < nE) {
    int p = atomicAdd(&cur[dst[e]], 1);
    sorted_src[p] = src[e];
  }
}

// ---------------- aggregation: one wave per dst node ----------------
__device__ __forceinline__ void acc_bf(float* acc, uint4 r) {
  acc[0] += bflo(r.x); acc[1] += bfhi(r.x);
  acc[2] += bflo(r.y); acc[3] += bfhi(r.y);
  acc[4] += bflo(r.z); acc[5] += bfhi(r.z);
  acc[6] += bflo(r.w); acc[7] += bfhi(r.w);
}

__device__ __forceinline__ void acc_f8(float* acc, uint2 r) {
  f32x2 a = __builtin_amdgcn_cvt_pk_f32_fp8(r.x, false);
  f32x2 b = __builtin_amdgcn_cvt_pk_f32_fp8(r.x, true);
  f32x2 c = __builtin_amdgcn_cvt_pk_f32_fp8(r.y, false);
  f32x2 d = __builtin_amdgcn_cvt_pk_f32_fp8(r.y, true);
  acc[0] += a.x; acc[1] += a.y; acc[2] += b.x; acc[3] += b.y;
  acc[4] += c.x; acc[5] += c.y; acc[6] += d.x; acc[7] += d.y;
}

__global__ void agg_kernel(unsigned short* __restrict__ Acat,
                           const unsigned char* __restrict__ h8,
                           const int* __restrict__ rowst,
                           const int* __restrict__ sorted_src, int n, int use_fp8) {
  int lane = threadIdx.x & 63;
  int node = blockIdx.x * 4 + (threadIdx.x >> 6);
  if (node >= n) return;
  int s0 = rowst[node], s1 = rowst[node + 1];
  float acc[8] = {0.f, 0.f, 0.f, 0.f, 0.f, 0.f, 0.f, 0.f};
  if (use_fp8) {
    const unsigned char* hb = h8 + lane * 8;
    int e = s0;
    for (; e + 3 < s1; e += 4) {
      int i0 = sorted_src[e], i1 = sorted_src[e + 1];
      int i2 = sorted_src[e + 2], i3 = sorted_src[e + 3];
      uint2 r0 = *(const uint2*)(hb + (size_t)i0 * 512);
      uint2 r1 = *(const uint2*)(hb + (size_t)i1 * 512);
      uint2 r2 = *(const uint2*)(hb + (size_t)i2 * 512);
      uint2 r3 = *(const uint2*)(hb + (size_t)i3 * 512);
      acc_f8(acc, r0); acc_f8(acc, r1); acc_f8(acc, r2); acc_f8(acc, r3);
    }
    for (; e < s1; ++e) {
      uint2 r0 = *(const uint2*)(hb + (size_t)sorted_src[e] * 512);
      acc_f8(acc, r0);
    }
  } else {
    const unsigned short* hbase = Acat + 512 + lane * 8;
    int e = s0;
    for (; e + 3 < s1; e += 4) {
      int i0 = sorted_src[e], i1 = sorted_src[e + 1];
      int i2 = sorted_src[e + 2], i3 = sorted_src[e + 3];
      uint4 r0 = *(const uint4*)(hbase + (size_t)i0 * 1024);
      uint4 r1 = *(const uint4*)(hbase + (size_t)i1 * 1024);
      uint4 r2 = *(const uint4*)(hbase + (size_t)i2 * 1024);
      uint4 r3 = *(const uint4*)(hbase + (size_t)i3 * 1024);
      acc_bf(acc, r0); acc_bf(acc, r1); acc_bf(acc, r2); acc_bf(acc, r3);
    }
    for (; e < s1; ++e) {
      uint4 r0 = *(const uint4*)(hbase + (size_t)sorted_src[e] * 1024);
      acc_bf(acc, r0);
    }
  }
  int deg = s1 - s0;
  float sc = (deg > 0) ? (1.0f / (float)deg) : 0.0f;
  uint4 st = { packbf2(acc[0] * sc, acc[1] * sc), packbf2(acc[2] * sc, acc[3] * sc),
               packbf2(acc[4] * sc, acc[5] * sc), packbf2(acc[6] * sc, acc[7] * sc) };
  *(uint4*)(Acat + (size_t)node * 1024 + lane * 8) = st;
}

// ---------------- GEMM: [Mpad x 1024] @ [512 x 1024]^T, m97 structure ----------------
__device__ __forceinline__ void async16(const unsigned short* g, char* lds) {
  __builtin_amdgcn_global_load_lds((const __attribute__((address_space(1))) void*)g,
                                   (__attribute__((address_space(3))) void*)lds, 16, 0, 0);
}

__global__ __launch_bounds__(256) void gemm_kernel(
    const unsigned short* __restrict__ A,  // [Mpad][1024] bf16 (mean | h)
    const unsigned short* __restrict__ B,  // [512][1024]  bf16 (W_l | W_r), row = out col
    const float* __restrict__ bias,        // b_l [512]
    const float* __restrict__ residual,    // x [M][512]
    float* __restrict__ out, int M) {
  __shared__ unsigned short sA[128 * 32];  // 8 KB
  __shared__ unsigned short sB[128 * 32];  // 8 KB
  const int K = 1024;
  int t = threadIdx.x;
  int lane = t & 63, wave = t >> 6;
  int quad = lane >> 4, l16 = lane & 15;
  int mb = blockIdx.x >> 2, nb = blockIdx.x & 3;  // 4 col-blocks adjacent -> A-tile L2 reuse
  int mBase = mb * 128, nBase = nb * 128;
  int wm = (wave & 1) * 64, wn = (wave >> 1) * 64;

  const unsigned short* gA = A + (size_t)(mBase + (t >> 2)) * K + (t & 3) * 8;
  const unsigned short* gB = B + (size_t)(nBase + (t >> 2)) * K + (t & 3) * 8;
  char* lA0 = (char*)sA + wave * 1024;
  char* lA1 = (char*)sA + 4096 + wave * 1024;
  char* lB0 = (char*)sB + wave * 1024;
  char* lB1 = (char*)sB + 4096 + wave * 1024;

  f32x4 acc[4][4] = {};

  for (int ks = 0; ks < K; ks += 32) {
    __syncthreads();
    async16(gA + ks, lA0);
    async16(gA + (size_t)64 * K + ks, lA1);
    async16(gB + ks, lB0);
    async16(gB + (size_t)64 * K + ks, lB1);
    __syncthreads();
    bf16x8 af[4], bf[4];
#pragma unroll
    for (int i = 0; i < 4; ++i)
      af[i] = *(const bf16x8*)(sA + (wm + i * 16 + l16) * 32 + quad * 8);
#pragma unroll
    for (int j = 0; j < 4; ++j)
      bf[j] = *(const bf16x8*)(sB + (wn + j * 16 + l16) * 32 + quad * 8);
#pragma unroll
    for (int i = 0; i < 4; ++i)
#pragma unroll
      for (int j = 0; j < 4; ++j)
        acc[i][j] = __builtin_amdgcn_mfma_f32_16x16x32_bf16(af[i], bf[j], acc[i][j], 0, 0, 0);
  }

  float biasv[4];
#pragma unroll
  for (int j = 0; j < 4; ++j) biasv[j] = bias[nBase + wn + j * 16 + l16];
#pragma unroll
  for (int i = 0; i < 4; ++i) {
    int gr0 = mBase + wm + i * 16 + quad * 4;  // C/D: row = quad*4+reg, col = lane&15
#pragma unroll
    for (int j = 0; j < 4; ++j) {
      int col = nBase + wn + j * 16 + l16;
#pragma unroll
      for (int r = 0; r < 4; ++r) {
        int gr = gr0 + r;
        if (gr < M) {
          size_t idx = (size_t)gr * D_DIM + col;
          float v = acc[i][j][r] + biasv[j];
          float rv = __builtin_nontemporal_load(&residual[idx]);
          __builtin_nontemporal_store(fmaxf(v, 0.0f) + rv, &out[idx]);
        }
      }
    }
  }
}

// ---------------- launch ----------------
extern "C" void kernel_launch(void* const* d_in, const int* in_sizes, int n_in,
                              void* d_out, int out_size, void* d_ws, size_t ws_size,
                              hipStream_t stream) {
  const float* x = (const float*)d_in[0];
  const int* ei = (const int*)d_in[1];
  const float* Wl = (const float*)d_in[2];
  const float* bl = (const float*)d_in[3];
  const float* Wr = (const float*)d_in[4];
  const float* gamma = (const float*)d_in[5];
  const float* beta = (const float*)d_in[6];
  float* out = (float*)d_out;

  int n = in_sizes[0] / D_DIM;       // 50000
  int nE = in_sizes[1] / 2;          // 1500000
  const int* src = ei;
  const int* dstv = ei + nE;
  int Mpad = (n + 127) & ~127;       // 50048

  char* w = (char*)d_ws;
  size_t off = 0;
  auto carve = [&](size_t bytes) {
    char* p = w + off;
    off += (bytes + 255) & ~(size_t)255;
    return p;
  };
  unsigned short* Acat = (unsigned short*)carve((size_t)Mpad * 1024 * 2);  // 102.5 MB
  unsigned short* Wcat = (unsigned short*)carve((size_t)512 * 1024 * 2);   // 1 MB
  int* sorted = (int*)carve((size_t)nE * 4);                               // 6 MB
  int* cnt = (int*)carve((size_t)n * 4);                                   // also 'cur'
  int* rowst = (int*)carve((size_t)(n + 1) * 4);
  int* bsums = (int*)carve(1024);
  if (off > ws_size) return;  // minimal set doesn't fit -> loud failure

  // fp8 gather copy of h, only if ws allows (+25.6 MB)
  size_t h8_bytes = (size_t)n * 512;
  int use_fp8 = (off + h8_bytes <= ws_size) ? 1 : 0;
  unsigned char* h8 = use_fp8 ? (unsigned char*)carve(h8_bytes) : (unsigned char*)w;

  int nbScan = (n + 1023) / 1024;  // 49 (<=64 required by scan2)

  ln_kernel<<<(n + 3) / 4, 256, 0, stream>>>(x, gamma, beta, Acat, h8, n, use_fp8);
  wconv_kernel<<<(512 * 512) / 256, 256, 0, stream>>>(Wl, Wr, Wcat);
  zero_kernel<<<(n + 255) / 256, 256, 0, stream>>>(cnt, n);
  hist_kernel<<<(nE + 255) / 256, 256, 0, stream>>>(dstv, nE, cnt);
  scan1_kernel<<<nbScan, 1024, 0, stream>>>(cnt, n, rowst, bsums);
  scan2_kernel<<<1, 64, 0, stream>>>(bsums, nbScan);
  scan3_kernel<<<nbScan, 1024, 0, stream>>>(rowst, cnt, bsums, n, nE);  // cur aliases cnt
  scatter_kernel<<<(nE + 255) / 256, 256, 0, stream>>>(src, dstv, nE, cnt, sorted);
  agg_kernel<<<(n + 3) / 4, 256, 0, stream>>>(Acat, h8, rowst, sorted, n, use_fp8);
  gemm_kernel<<<(Mpad / 128) * 4, 256, 0, stream>>>(Acat, Wcat, bl, x, out, n);
}

// Round 3
// 647.633 us; speedup vs baseline: 1.1371x; 1.0071x over previous
//
#include <hip/hip_runtime.h>

// GNN encoder layer: LN -> mean-aggregate over edges -> SAGEConv -> relu -> +residual
// Pipeline (all on `stream`, graph-capture safe):
//  1. ln_kernel      : h = LN(x)*gamma+beta -> bf16 into A_cat[:,512:1024], fp8 copy into h8
//  2. wconv_kernel   : W_cat[j,0:512]=bf16(W_l[j,:]), W_cat[j,512:1024]=bf16(W_r[j,:])
//  3. zero + hist    : cnt[d] = in-degree
//  4. scan1/2/3      : row_start = exclusive_scan(cnt); cur(=cnt) = row_start
//  5. scatter_kernel : sorted_src = src indices grouped by dst (CSR)
//  6. agg_kernel     : mean of fp8 h rows (fp32 accum) -> bf16 into A_cat[:,0:512]
//  7. gemm_kernel    : out = relu(A_cat @ W_cat^T + b_l) + residual
//     - LDS double-buffered, raw s_waitcnt vmcnt(4)+s_barrier so prefetch survives
//       the barrier (round-2 showed latency-bound: MfmaUtil 11%, 2.2 TB/s)
//     - XCD swizzle: 4 N-sibling blocks of one A-tile land on one XCD's L2

#define D_DIM 512

typedef __bf16 bf16x8 __attribute__((ext_vector_type(8)));
typedef float f32x4 __attribute__((ext_vector_type(4)));
typedef float f32x2 __attribute__((ext_vector_type(2)));

__device__ __forceinline__ unsigned short f2bf(float f) {
  unsigned u = __float_as_uint(f);
  u += 0x7fffu + ((u >> 16) & 1u);   // RNE
  return (unsigned short)(u >> 16);
}
__device__ __forceinline__ float bflo(unsigned u) { return __uint_as_float(u << 16); }
__device__ __forceinline__ float bfhi(unsigned u) { return __uint_as_float(u & 0xffff0000u); }
__device__ __forceinline__ unsigned packbf2(float lo, float hi) {
  return (unsigned)f2bf(lo) | ((unsigned)f2bf(hi) << 16);
}

// ---------------- LayerNorm: one wave per row, 8 floats/lane ----------------
__global__ void ln_kernel(const float* __restrict__ x, const float* __restrict__ gamma,
                          const float* __restrict__ beta, unsigned short* __restrict__ Acat,
                          unsigned char* __restrict__ h8, int n, int use_fp8) {
  int lane = threadIdx.x & 63;
  int row = blockIdx.x * 4 + (threadIdx.x >> 6);
  if (row >= n) return;
  const float* xr = x + (size_t)row * D_DIM + lane * 8;
  float4 a = *(const float4*)xr;
  float4 b = *(const float4*)(xr + 4);
  float sum = a.x + a.y + a.z + a.w + b.x + b.y + b.z + b.w;
  float sq = a.x * a.x + a.y * a.y + a.z * a.z + a.w * a.w +
             b.x * b.x + b.y * b.y + b.z * b.z + b.w * b.w;
#pragma unroll
  for (int m = 1; m < 64; m <<= 1) {
    sum += __shfl_xor(sum, m, 64);
    sq  += __shfl_xor(sq, m, 64);
  }
  float mu = sum * (1.0f / D_DIM);
  float var = sq * (1.0f / D_DIM) - mu * mu;
  float rs = rsqrtf(var + 1e-5f);
  const float* gp = gamma + lane * 8;
  const float* bp = beta + lane * 8;
  float4 g0 = *(const float4*)gp, g1 = *(const float4*)(gp + 4);
  float4 e0 = *(const float4*)bp, e1 = *(const float4*)(bp + 4);
  float h0 = (a.x - mu) * rs * g0.x + e0.x;
  float h1 = (a.y - mu) * rs * g0.y + e0.y;
  float h2 = (a.z - mu) * rs * g0.z + e0.z;
  float h3 = (a.w - mu) * rs * g0.w + e0.w;
  float h4 = (b.x - mu) * rs * g1.x + e1.x;
  float h5 = (b.y - mu) * rs * g1.y + e1.y;
  float h6 = (b.z - mu) * rs * g1.z + e1.z;
  float h7 = (b.w - mu) * rs * g1.w + e1.w;
  uint4 st = { packbf2(h0, h1), packbf2(h2, h3), packbf2(h4, h5), packbf2(h6, h7) };
  *(uint4*)(Acat + (size_t)row * 1024 + 512 + lane * 8) = st;
  if (use_fp8) {
    int p0 = __builtin_amdgcn_cvt_pk_fp8_f32(h0, h1, 0, false);
    p0 = __builtin_amdgcn_cvt_pk_fp8_f32(h2, h3, p0, true);
    int p1 = __builtin_amdgcn_cvt_pk_fp8_f32(h4, h5, 0, false);
    p1 = __builtin_amdgcn_cvt_pk_fp8_f32(h6, h7, p1, true);
    uint2 st2 = { (unsigned)p0, (unsigned)p1 };
    *(uint2*)(h8 + (size_t)row * 512 + lane * 8) = st2;
  }
}

// ---------------- W concat + bf16 convert ----------------
__global__ void wconv_kernel(const float* __restrict__ Wl, const float* __restrict__ Wr,
                             unsigned short* __restrict__ Wcat) {
  int id = blockIdx.x * 256 + threadIdx.x;  // 0 .. 512*512-1
  int j = id >> 9, k = id & 511;
  Wcat[(size_t)j * 1024 + k] = f2bf(Wl[id]);
  Wcat[(size_t)j * 1024 + 512 + k] = f2bf(Wr[id]);
}

// ---------------- CSR build ----------------
__global__ void zero_kernel(int* __restrict__ p, int n) {
  int i = blockIdx.x * 256 + threadIdx.x;
  if (i < n) p[i] = 0;
}

__global__ void hist_kernel(const int* __restrict__ dst, int nE, int* __restrict__ cnt) {
  int e = blockIdx.x * 256 + threadIdx.x;
  if (e < nE) atomicAdd(&cnt[dst[e]], 1);
}

__global__ void scan1_kernel(const int* __restrict__ cnt, int n,
                             int* __restrict__ excl, int* __restrict__ bsums) {
  __shared__ int wsum[16];
  int gid = blockIdx.x * 1024 + threadIdx.x;
  int lane = threadIdx.x & 63, wave = threadIdx.x >> 6;
  int v = (gid < n) ? cnt[gid] : 0;
  int s = v;
#pragma unroll
  for (int d = 1; d < 64; d <<= 1) {
    int t = __shfl_up(s, d, 64);
    if (lane >= d) s += t;
  }
  if (lane == 63) wsum[wave] = s;
  __syncthreads();
  if (wave == 0) {
    int ws = (lane < 16) ? wsum[lane] : 0;
#pragma unroll
    for (int d = 1; d < 16; d <<= 1) {
      int t = __shfl_up(ws, d, 64);
      if (lane >= d) ws += t;
    }
    if (lane < 16) wsum[lane] = ws;
  }
  __syncthreads();
  int incl = s + ((wave > 0) ? wsum[wave - 1] : 0);
  if (gid < n) excl[gid] = incl - v;
  if (threadIdx.x == 1023) bsums[blockIdx.x] = incl;
}

__global__ void scan2_kernel(int* __restrict__ bsums, int nb) {
  int lane = threadIdx.x;  // 64 threads, nb <= 64
  int v = (lane < nb) ? bsums[lane] : 0;
  int s = v;
#pragma unroll
  for (int d = 1; d < 64; d <<= 1) {
    int t = __shfl_up(s, d, 64);
    if (lane >= d) s += t;
  }
  if (lane < nb) bsums[lane] = s - v;  // exclusive
}

__global__ void scan3_kernel(int* __restrict__ rowst, int* __restrict__ cur,
                             const int* __restrict__ bsums, int n, int nE) {
  int gid = blockIdx.x * 1024 + threadIdx.x;
  if (gid < n) {
    int r = rowst[gid] + bsums[blockIdx.x];
    rowst[gid] = r;
    cur[gid] = r;
  }
  if (gid == 0) rowst[n] = nE;
}

__global__ void scatter_kernel(const int* __restrict__ src, const int* __restrict__ dst,
                               int nE, int* __restrict__ cur, int* __restrict__ sorted_src) {
  int e = blockIdx.x * 256 + threadIdx.x;
  if (e < nE) {
    int p = atomicAdd(&cur[dst[e]], 1);
    sorted_src[p] = src[e];
  }
}

// ---------------- aggregation: one wave per dst node ----------------
__device__ __forceinline__ void acc_bf(float* acc, uint4 r) {
  acc[0] += bflo(r.x); acc[1] += bfhi(r.x);
  acc[2] += bflo(r.y); acc[3] += bfhi(r.y);
  acc[4] += bflo(r.z); acc[5] += bfhi(r.z);
  acc[6] += bflo(r.w); acc[7] += bfhi(r.w);
}

__device__ __forceinline__ void acc_f8(float* acc, uint2 r) {
  f32x2 a = __builtin_amdgcn_cvt_pk_f32_fp8(r.x, false);
  f32x2 b = __builtin_amdgcn_cvt_pk_f32_fp8(r.x, true);
  f32x2 c = __builtin_amdgcn_cvt_pk_f32_fp8(r.y, false);
  f32x2 d = __builtin_amdgcn_cvt_pk_f32_fp8(r.y, true);
  acc[0] += a.x; acc[1] += a.y; acc[2] += b.x; acc[3] += b.y;
  acc[4] += c.x; acc[5] += c.y; acc[6] += d.x; acc[7] += d.y;
}

__global__ void agg_kernel(unsigned short* __restrict__ Acat,
                           const unsigned char* __restrict__ h8,
                           const int* __restrict__ rowst,
                           const int* __restrict__ sorted_src, int n, int use_fp8) {
  int lane = threadIdx.x & 63;
  int node = blockIdx.x * 4 + (threadIdx.x >> 6);
  if (node >= n) return;
  int s0 = rowst[node], s1 = rowst[node + 1];
  float acc[8] = {0.f, 0.f, 0.f, 0.f, 0.f, 0.f, 0.f, 0.f};
  if (use_fp8) {
    const unsigned char* hb = h8 + lane * 8;
    int e = s0;
    for (; e + 3 < s1; e += 4) {
      int i0 = sorted_src[e], i1 = sorted_src[e + 1];
      int i2 = sorted_src[e + 2], i3 = sorted_src[e + 3];
      uint2 r0 = *(const uint2*)(hb + (size_t)i0 * 512);
      uint2 r1 = *(const uint2*)(hb + (size_t)i1 * 512);
      uint2 r2 = *(const uint2*)(hb + (size_t)i2 * 512);
      uint2 r3 = *(const uint2*)(hb + (size_t)i3 * 512);
      acc_f8(acc, r0); acc_f8(acc, r1); acc_f8(acc, r2); acc_f8(acc, r3);
    }
    for (; e < s1; ++e) {
      uint2 r0 = *(const uint2*)(hb + (size_t)sorted_src[e] * 512);
      acc_f8(acc, r0);
    }
  } else {
    const unsigned short* hbase = Acat + 512 + lane * 8;
    int e = s0;
    for (; e + 3 < s1; e += 4) {
      int i0 = sorted_src[e], i1 = sorted_src[e + 1];
      int i2 = sorted_src[e + 2], i3 = sorted_src[e + 3];
      uint4 r0 = *(const uint4*)(hbase + (size_t)i0 * 1024);
      uint4 r1 = *(const uint4*)(hbase + (size_t)i1 * 1024);
      uint4 r2 = *(const uint4*)(hbase + (size_t)i2 * 1024);
      uint4 r3 = *(const uint4*)(hbase + (size_t)i3 * 1024);
      acc_bf(acc, r0); acc_bf(acc, r1); acc_bf(acc, r2); acc_bf(acc, r3);
    }
    for (; e < s1; ++e) {
      uint4 r0 = *(const uint4*)(hbase + (size_t)sorted_src[e] * 1024);
      acc_bf(acc, r0);
    }
  }
  int deg = s1 - s0;
  float sc = (deg > 0) ? (1.0f / (float)deg) : 0.0f;
  uint4 st = { packbf2(acc[0] * sc, acc[1] * sc), packbf2(acc[2] * sc, acc[3] * sc),
               packbf2(acc[4] * sc, acc[5] * sc), packbf2(acc[6] * sc, acc[7] * sc) };
  *(uint4*)(Acat + (size_t)node * 1024 + lane * 8) = st;
}

// ---------------- GEMM: [Mpad x 1024] @ [512 x 1024]^T, pipelined ----------------
__device__ __forceinline__ void async16(const unsigned short* g, char* lds) {
  __builtin_amdgcn_global_load_lds((const __attribute__((address_space(1))) void*)g,
                                   (__attribute__((address_space(3))) void*)lds, 16, 0, 0);
}

__global__ __launch_bounds__(256) void gemm_kernel(
    const unsigned short* __restrict__ A,  // [Mpad][1024] bf16 (mean | h)
    const unsigned short* __restrict__ B,  // [512][1024]  bf16 (W_l | W_r), row = out col
    const float* __restrict__ bias,        // b_l [512]
    const float* __restrict__ residual,    // x [M][512]
    float* __restrict__ out, int M, int Mblocks) {
  __shared__ unsigned short sA[2][4096];  // 2 x 8 KB (128 rows x 32 k)
  __shared__ unsigned short sB[2][4096];
  const int K = 1024;
  int t = threadIdx.x;
  int lane = t & 63, wave = t >> 6;
  int quad = lane >> 4, l16 = lane & 15;
  // XCD swizzle: blocks b, b+8, b+16, b+24 (same XCD under %8 round-robin)
  // are the 4 N-siblings of one A-tile -> A-tile served from that XCD's L2.
  int b = blockIdx.x;
  int mb = (b >> 5) * 8 + (b & 7);
  int nb = (b >> 3) & 3;
  if (mb >= Mblocks) return;
  int mBase = mb * 128, nBase = nb * 128;
  int wm = (wave & 1) * 64, wn = (wave >> 1) * 64;

  const unsigned short* gA = A + (size_t)(mBase + (t >> 2)) * K + (t & 3) * 8;
  const unsigned short* gB = B + (size_t)(nBase + (t >> 2)) * K + (t & 3) * 8;

  f32x4 acc[4][4] = {};

  auto issue = [&](int ks, int buf) {
    char* a0 = (char*)&sA[buf][0] + wave * 1024;
    char* b0 = (char*)&sB[buf][0] + wave * 1024;
    async16(gA + ks, a0);
    async16(gA + (size_t)64 * K + ks, a0 + 4096);
    async16(gB + ks, b0);
    async16(gB + (size_t)64 * K + ks, b0 + 4096);
  };
  auto compute = [&](int buf) {
    const unsigned short* pA = &sA[buf][0];
    const unsigned short* pB = &sB[buf][0];
    bf16x8 af[4], bfr[4];
#pragma unroll
    for (int i = 0; i < 4; ++i)
      af[i] = *(const bf16x8*)(pA + (wm + i * 16 + l16) * 32 + quad * 8);
#pragma unroll
    for (int j = 0; j < 4; ++j)
      bfr[j] = *(const bf16x8*)(pB + (wn + j * 16 + l16) * 32 + quad * 8);
#pragma unroll
    for (int i = 0; i < 4; ++i)
#pragma unroll
      for (int j = 0; j < 4; ++j)
        acc[i][j] = __builtin_amdgcn_mfma_f32_16x16x32_bf16(af[i], bfr[j], acc[i][j], 0, 0, 0);
  };

  issue(0, 0);
  for (int r = 0; r < 31; ++r) {
    int cur = r & 1;
    issue((r + 1) << 5, cur ^ 1);
    // wait for the OLDEST 4 loads (tile r), keep tile r+1's 4 in flight
    asm volatile("s_waitcnt vmcnt(4)\n\ts_barrier" ::: "memory");
    compute(cur);
    // all waves done reading buf[cur] before round r+1 overwrites it
    asm volatile("s_barrier" ::: "memory");
  }
  asm volatile("s_waitcnt vmcnt(0)\n\ts_barrier" ::: "memory");
  compute(1);  // tile 31 lives in buf 1

  float biasv[4];
#pragma unroll
  for (int j = 0; j < 4; ++j) biasv[j] = bias[nBase + wn + j * 16 + l16];
#pragma unroll
  for (int i = 0; i < 4; ++i) {
    int gr0 = mBase + wm + i * 16 + quad * 4;  // C/D: row = quad*4+reg, col = lane&15
#pragma unroll
    for (int j = 0; j < 4; ++j) {
      int col = nBase + wn + j * 16 + l16;
#pragma unroll
      for (int r = 0; r < 4; ++r) {
        int gr = gr0 + r;
        if (gr < M) {
          size_t idx = (size_t)gr * D_DIM + col;
          float v = acc[i][j][r] + biasv[j];
          float rv = __builtin_nontemporal_load(&residual[idx]);
          __builtin_nontemporal_store(fmaxf(v, 0.0f) + rv, &out[idx]);
        }
      }
    }
  }
}

// ---------------- launch ----------------
extern "C" void kernel_launch(void* const* d_in, const int* in_sizes, int n_in,
                              void* d_out, int out_size, void* d_ws, size_t ws_size,
                              hipStream_t stream) {
  const float* x = (const float*)d_in[0];
  const int* ei = (const int*)d_in[1];
  const float* Wl = (const float*)d_in[2];
  const float* bl = (const float*)d_in[3];
  const float* Wr = (const float*)d_in[4];
  const float* gamma = (const float*)d_in[5];
  const float* beta = (const float*)d_in[6];
  float* out = (float*)d_out;

  int n = in_sizes[0] / D_DIM;       // 50000
  int nE = in_sizes[1] / 2;          // 1500000
  const int* src = ei;
  const int* dstv = ei + nE;
  int Mpad = (n + 127) & ~127;       // 50048
  int Mblocks = Mpad / 128;          // 391

  char* w = (char*)d_ws;
  size_t off = 0;
  auto carve = [&](size_t bytes) {
    char* p = w + off;
    off += (bytes + 255) & ~(size_t)255;
    return p;
  };
  unsigned short* Acat = (unsigned short*)carve((size_t)Mpad * 1024 * 2);  // 102.5 MB
  unsigned short* Wcat = (unsigned short*)carve((size_t)512 * 1024 * 2);   // 1 MB
  int* sorted = (int*)carve((size_t)nE * 4);                               // 6 MB
  int* cnt = (int*)carve((size_t)n * 4);                                   // also 'cur'
  int* rowst = (int*)carve((size_t)(n + 1) * 4);
  int* bsums = (int*)carve(1024);
  if (off > ws_size) return;  // minimal set doesn't fit -> loud failure

  // fp8 gather copy of h, only if ws allows (+25.6 MB)
  size_t h8_bytes = (size_t)n * 512;
  int use_fp8 = (off + h8_bytes <= ws_size) ? 1 : 0;
  unsigned char* h8 = use_fp8 ? (unsigned char*)carve(h8_bytes) : (unsigned char*)w;

  int nbScan = (n + 1023) / 1024;  // 49 (<=64 required by scan2)

  ln_kernel<<<(n + 3) / 4, 256, 0, stream>>>(x, gamma, beta, Acat, h8, n, use_fp8);
  wconv_kernel<<<(512 * 512) / 256, 256, 0, stream>>>(Wl, Wr, Wcat);
  zero_kernel<<<(n + 255) / 256, 256, 0, stream>>>(cnt, n);
  hist_kernel<<<(nE + 255) / 256, 256, 0, stream>>>(dstv, nE, cnt);
  scan1_kernel<<<nbScan, 1024, 0, stream>>>(cnt, n, rowst, bsums);
  scan2_kernel<<<1, 64, 0, stream>>>(bsums, nbScan);
  scan3_kernel<<<nbScan, 1024, 0, stream>>>(rowst, cnt, bsums, n, nE);  // cur aliases cnt
  scatter_kernel<<<(nE + 255) / 256, 256, 0, stream>>>(src, dstv, nE, cnt, sorted);
  agg_kernel<<<(n + 3) / 4, 256, 0, stream>>>(Acat, h8, rowst, sorted, n, use_fp8);
  // grid covers mb in [0, 392) x nb in [0,4); mb==391 blocks early-exit
  int gemmBlocks = ((Mblocks + 7) / 8) * 32;  // 1568
  gemm_kernel<<<gemmBlocks, 256, 0, stream>>>(Acat, Wcat, bl, x, out, n, Mblocks);
}